// Round 7
// baseline (64.437 us; speedup 1.0000x reference)
//
#include <hip/hip_runtime.h>
#include <math.h>

// Problem constants (from reference setup_inputs): B=32, N=256, D=32.
#define BB 32
#define NN 256
#define DD 32
#define RPT 4                    // A-rows per thread (held in registers)
#define TPB 64                   // one wave per block; 64*RPT = 256 rows
#define SPLIT 16                 // j-dimension split per (batch,type)
#define JCHUNK (NN / SPLIT)      // 16 j's per block
#define NPART (BB * 3 * SPLIT)   // 1536 blocks / partials
#define PART_OFF 64              // float offset of partials within ws

// Register pin: makes v opaque to the compiler so it CANNOT rematerialize
// (re-load from global) the value inside the loop. This was the R1-R6
// killer: LLVM sank the A-row loads into the j-loop (VGPR=100, FETCH 4x,
// no spill traffic -> remat, not spill).
__device__ __forceinline__ void pin4(float4& v) {
    asm volatile("" : "+v"(v.x), "+v"(v.y), "+v"(v.z), "+v"(v.w));
}

__global__ void mmd_init(unsigned int* cnt) { *cnt = 0u; }

// type 0: (x,x) +1 | type 1: (y,y) +1 | type 2: (x,y) -2
__global__ __launch_bounds__(TPB, 1) void mmd_fused(
    const float* __restrict__ x, const float* __restrict__ y,
    const float* __restrict__ w, float* __restrict__ ws,
    float* __restrict__ out) {
    unsigned int* cnt = (unsigned int*)ws;
    float* partials = ws + PART_OFF;

    const int blk  = blockIdx.x;
    const int s    = blk & (SPLIT - 1);
    const int bt   = blk / SPLIT;
    const int type = bt % 3;
    const int b    = bt / 3;
    const int tid  = threadIdx.x;

    const float* Arow_base = (type == 1) ? y : x;   // rows (i)
    const float* Bcol_base = (type == 0) ? x : y;   // cols (j)

    // 4 A-rows per thread, rows i = r*64 + tid. Loaded ONCE, then pinned.
    float4 a[RPT][DD / 4];
    #pragma unroll
    for (int r = 0; r < RPT; ++r) {
        const float4* ar =
            (const float4*)(Arow_base + ((size_t)b * NN + r * TPB + tid) * DD);
        #pragma unroll
        for (int k = 0; k < DD / 4; ++k) a[r][k] = ar[k];
    }
    #pragma unroll
    for (int r = 0; r < RPT; ++r)
        #pragma unroll
        for (int k = 0; k < DD / 4; ++k) pin4(a[r][k]);

    // Stage the 16 B-rows in LDS (128 float4 = 2 stores/thread).
    __shared__ float4 bs4[JCHUNK * (DD / 4)];
    __shared__ float b2s[JCHUNK];
    {
        const float4* bb =
            (const float4*)(Bcol_base + ((size_t)b * NN + s * JCHUNK) * DD);
        bs4[tid] = bb[tid];
        bs4[tid + TPB] = bb[tid + TPB];
    }

    float a2[RPT];
    #pragma unroll
    for (int r = 0; r < RPT; ++r) {
        float4 s2 = make_float4(0.f, 0.f, 0.f, 0.f);
        #pragma unroll
        for (int k = 0; k < DD / 4; ++k) {
            float4 v = a[r][k];
            s2.x = fmaf(v.x, v.x, s2.x);
            s2.y = fmaf(v.y, v.y, s2.y);
            s2.z = fmaf(v.z, v.z, s2.z);
            s2.w = fmaf(v.w, v.w, s2.w);
        }
        a2[r] = (s2.x + s2.y) + (s2.z + s2.w);
        asm volatile("" : "+v"(a2[r]));
    }

    __syncthreads();
    if (tid < JCHUNK) {
        float4 s2 = make_float4(0.f, 0.f, 0.f, 0.f);
        #pragma unroll
        for (int k = 0; k < DD / 4; ++k) {
            float4 v = bs4[tid * (DD / 4) + k];
            s2.x = fmaf(v.x, v.x, s2.x);
            s2.y = fmaf(v.y, v.y, s2.y);
            s2.z = fmaf(v.z, v.z, s2.z);
            s2.w = fmaf(v.w, v.w, s2.w);
        }
        b2s[tid] = (s2.x + s2.y) + (s2.z + s2.w);
    }
    __syncthreads();

    const float negw = -w[b] * (1.0f / (float)DD);

    float acc[RPT] = {0.f, 0.f, 0.f, 0.f};
    #pragma unroll 4
    for (int j = 0; j < JCHUNK; ++j) {
        const float b2 = b2s[j];
        float4 dv[RPT];
        #pragma unroll
        for (int r = 0; r < RPT; ++r) dv[r] = make_float4(0.f, 0.f, 0.f, 0.f);
        #pragma unroll
        for (int k = 0; k < DD / 4; ++k) {
            const float4 bv = bs4[j * (DD / 4) + k];   // uniform -> broadcast
            #pragma unroll
            for (int r = 0; r < RPT; ++r) {
                dv[r].x = fmaf(a[r][k].x, bv.x, dv[r].x);
                dv[r].y = fmaf(a[r][k].y, bv.y, dv[r].y);
                dv[r].z = fmaf(a[r][k].z, bv.z, dv[r].z);
                dv[r].w = fmaf(a[r][k].w, bv.w, dv[r].w);
            }
        }
        #pragma unroll
        for (int r = 0; r < RPT; ++r) {
            const float dot = (dv[r].x + dv[r].y) + (dv[r].z + dv[r].w);
            float sq = fmaf(-2.0f, dot, a2[r] + b2);
            sq = fmaxf(sq, 1e-8f);   // folds norm clamp: sqrt(1e-8) = 1e-4
            acc[r] += __expf(negw * __builtin_amdgcn_sqrtf(sq));
        }
    }

    // Deterministic wave64 reduction.
    float tsum = (acc[0] + acc[1]) + (acc[2] + acc[3]);
    #pragma unroll
    for (int off = 32; off > 0; off >>= 1) tsum += __shfl_down(tsum, off, 64);

    // Publish partial + last-block finale (fixed-order double sum —
    // deterministic regardless of which block arrives last).
    unsigned int old = 0u;
    if (tid == 0) {
        const float weight = (type == 2) ? -2.0f : 1.0f;
        const float scale  = weight / ((float)NN * (float)NN * (float)BB);
        __hip_atomic_store(&partials[blk], tsum * scale,
                           __ATOMIC_RELEASE, __HIP_MEMORY_SCOPE_AGENT);
        old = __hip_atomic_fetch_add(cnt, 1u, __ATOMIC_ACQ_REL,
                                     __HIP_MEMORY_SCOPE_AGENT);
    }
    old = (unsigned int)__builtin_amdgcn_readfirstlane((int)old);
    if (old == NPART - 1) {
        double sum = 0.0;
        #pragma unroll
        for (int t = 0; t < NPART / TPB; ++t) {
            float p = __hip_atomic_load(&partials[tid + t * TPB],
                                        __ATOMIC_RELAXED,
                                        __HIP_MEMORY_SCOPE_AGENT);
            sum += (double)p;
        }
        #pragma unroll
        for (int off = 32; off > 0; off >>= 1) sum += __shfl_down(sum, off, 64);
        if (tid == 0) out[0] = (float)sum;
    }
}

extern "C" void kernel_launch(void* const* d_in, const int* in_sizes, int n_in,
                              void* d_out, int out_size, void* d_ws, size_t ws_size,
                              hipStream_t stream) {
    const float* x = (const float*)d_in[0];
    const float* y = (const float*)d_in[1];
    const float* w = (const float*)d_in[2];
    float* out = (float*)d_out;
    float* ws  = (float*)d_ws;   // [0]: counter, [PART_OFF..]: NPART partials

    mmd_init<<<1, 1, 0, stream>>>((unsigned int*)ws);
    mmd_fused<<<NPART, TPB, 0, stream>>>(x, y, w, ws, out);
}

// Round 8
// 22.431 us; speedup vs baseline: 2.8727x; 2.8727x over previous
//
#include <hip/hip_runtime.h>
#include <math.h>

// Problem constants (from reference setup_inputs): B=32, N=256, D=32.
#define BB 32
#define NN 256
#define DD 32
#define TPB 256                  // 4 waves; thread = one i-row
#define SPLIT 8                  // j-dimension split per (batch,type)
#define JCHUNK (NN / SPLIT)      // 32 j's per block
#define NPART (BB * 3 * SPLIT)   // 768 blocks / partials

__device__ __forceinline__ void pin4(float4& v) {
    asm volatile("" : "+v"(v.x), "+v"(v.y), "+v"(v.z), "+v"(v.w));
}

// type 0: (x,x) +1 | type 1: (y,y) +1 | type 2: (x,y) -2
// No atomics anywhere (R5-R7 lesson: 1536 same-address acq-rel RMWs
// serialize at ~22ns each = 35-70us). Two-kernel deterministic reduction.
__global__ __launch_bounds__(TPB, 4) void mmd_partial(
    const float* __restrict__ x, const float* __restrict__ y,
    const float* __restrict__ w, float* __restrict__ partials) {
    const int blk  = blockIdx.x;
    const int s    = blk & (SPLIT - 1);
    const int bt   = blk / SPLIT;
    const int type = bt % 3;
    const int b    = bt / 3;
    const int tid  = threadIdx.x;

    const float* Arow_base = (type == 1) ? y : x;   // rows (i)
    const float* Bcol_base = (type == 0) ? x : y;   // cols (j)

    // One i-row per thread in registers (8 float4 = 32 VGPRs).
    float4 a[DD / 4];
    {
        const float4* ar =
            (const float4*)(Arow_base + ((size_t)b * NN + tid) * DD);
        #pragma unroll
        for (int k = 0; k < DD / 4; ++k) a[k] = ar[k];
    }
    #pragma unroll
    for (int k = 0; k < DD / 4; ++k) pin4(a[k]);

    // |a|^2 with the 4-chain structure (must match dot & b2 chains exactly
    // so the xx/yy diagonal cancels to exact 0 before the clamp).
    float a2;
    {
        float c0 = 0.f, c1 = 0.f, c2 = 0.f, c3 = 0.f;
        #pragma unroll
        for (int k = 0; k < DD / 4; ++k) {
            float4 v = a[k];
            c0 = fmaf(v.x, v.x, c0);
            c1 = fmaf(v.y, v.y, c1);
            c2 = fmaf(v.z, v.z, c2);
            c3 = fmaf(v.w, v.w, c3);
        }
        a2 = (c0 + c1) + (c2 + c3);
    }

    // Stage 32 B-rows (4 KB) in LDS: exactly 1 float4 store per thread.
    __shared__ float4 bs4[JCHUNK * (DD / 4)];
    __shared__ float b2s[JCHUNK];
    {
        const float4* bb =
            (const float4*)(Bcol_base + ((size_t)b * NN + s * JCHUNK) * DD);
        bs4[tid] = bb[tid];
    }
    __syncthreads();
    if (tid < JCHUNK) {
        float c0 = 0.f, c1 = 0.f, c2 = 0.f, c3 = 0.f;
        #pragma unroll
        for (int k = 0; k < DD / 4; ++k) {
            float4 v = bs4[tid * (DD / 4) + k];
            c0 = fmaf(v.x, v.x, c0);
            c1 = fmaf(v.y, v.y, c1);
            c2 = fmaf(v.z, v.z, c2);
            c3 = fmaf(v.w, v.w, c3);
        }
        b2s[tid] = (c0 + c1) + (c2 + c3);
    }
    __syncthreads();

    const float negw = -w[b] * (1.0f / (float)DD);

    float acc = 0.f;
    #pragma unroll 4
    for (int j = 0; j < JCHUNK; ++j) {
        float c0 = 0.f, c1 = 0.f, c2 = 0.f, c3 = 0.f;
        #pragma unroll
        for (int k = 0; k < DD / 4; ++k) {
            const float4 bv = bs4[j * (DD / 4) + k];   // uniform -> broadcast
            c0 = fmaf(a[k].x, bv.x, c0);
            c1 = fmaf(a[k].y, bv.y, c1);
            c2 = fmaf(a[k].z, bv.z, c2);
            c3 = fmaf(a[k].w, bv.w, c3);
        }
        const float dot = (c0 + c1) + (c2 + c3);
        float sq = fmaf(-2.0f, dot, a2 + b2s[j]);
        sq = fmaxf(sq, 1e-8f);   // folds norm clamp: sqrt(1e-8) = 1e-4
        acc += __expf(negw * __builtin_amdgcn_sqrtf(sq));
    }

    // Deterministic block reduction: wave shuffle + fixed-order cross-wave.
    #pragma unroll
    for (int off = 32; off > 0; off >>= 1) acc += __shfl_down(acc, off, 64);
    __shared__ float red[TPB / 64];
    if ((tid & 63) == 0) red[tid >> 6] = acc;
    __syncthreads();
    if (tid == 0) {
        const float bsum = (red[0] + red[1]) + (red[2] + red[3]);
        const float weight = (type == 2) ? -2.0f : 1.0f;
        const float scale  = weight / ((float)NN * (float)NN * (float)BB);
        partials[blk] = bsum * scale;
    }
}

// Final deterministic reduction of NPART partials in double.
__global__ __launch_bounds__(256) void mmd_reduce(
    const float* __restrict__ partials, float* __restrict__ out) {
    double acc = 0.0;
    #pragma unroll
    for (int t = 0; t < NPART / 256; ++t)
        acc += (double)partials[threadIdx.x + t * 256];
    #pragma unroll
    for (int off = 32; off > 0; off >>= 1) acc += __shfl_down(acc, off, 64);
    __shared__ double red[4];
    if ((threadIdx.x & 63) == 0) red[threadIdx.x >> 6] = acc;
    __syncthreads();
    if (threadIdx.x == 0)
        out[0] = (float)((red[0] + red[1]) + (red[2] + red[3]));
}

extern "C" void kernel_launch(void* const* d_in, const int* in_sizes, int n_in,
                              void* d_out, int out_size, void* d_ws, size_t ws_size,
                              hipStream_t stream) {
    const float* x = (const float*)d_in[0];
    const float* y = (const float*)d_in[1];
    const float* w = (const float*)d_in[2];
    float* out = (float*)d_out;
    float* partials = (float*)d_ws;  // NPART floats

    mmd_partial<<<NPART, TPB, 0, stream>>>(x, y, w, partials);
    mmd_reduce<<<1, 256, 0, stream>>>(partials, out);
}

// Round 9
// 20.345 us; speedup vs baseline: 3.1672x; 1.1025x over previous
//
#include <hip/hip_runtime.h>
#include <math.h>

// Problem constants (from reference setup_inputs): B=32, N=256, D=32.
#define BB 32
#define NN 256
#define DD 32
#define TPB 256                  // 4 waves: wave = (row-half, j-subchunk)
#define RPT 2                    // A-rows per thread (held in registers)
#define SPLIT 8                  // j-chunks per (batch,type)
#define JCHUNK (NN / SPLIT)      // 32 j's staged per block
#define SJ (JCHUNK / 2)          // 16 j's per wave
#define NPART (BB * 3 * SPLIT)   // 768 blocks / partials

__device__ __forceinline__ void pin4(float4& v) {
    asm volatile("" : "+v"(v.x), "+v"(v.y), "+v"(v.z), "+v"(v.w));
}

// type 0: (x,x) +1 | type 1: (y,y) +1 | type 2: (x,y) -2
// LDS-issue analysis (R8 post-mortem): broadcast ds_read costs full issue
// slots on the one LDS pipe per CU. RPT=2 serves each B-read to 2 rows,
// halving LDS instructions per pair. No atomics (R5-R7 lesson).
__global__ __launch_bounds__(TPB, 2) void mmd_partial(
    const float* __restrict__ x, const float* __restrict__ y,
    const float* __restrict__ w, float* __restrict__ partials) {
    const int blk  = blockIdx.x;
    const int s    = blk & (SPLIT - 1);
    const int bt   = blk / SPLIT;
    const int type = bt % 3;
    const int b    = bt / 3;
    const int tid  = threadIdx.x;
    const int wave = tid >> 6;
    const int lane = tid & 63;
    const int h    = wave & 1;       // row-half: rows h*128 + {lane, lane+64}
    const int jj   = wave >> 1;      // j-subchunk: [jj*SJ, jj*SJ+SJ)

    const float* Arow_base = (type == 1) ? y : x;   // rows (i)
    const float* Bcol_base = (type == 0) ? x : y;   // cols (j)

    // 2 A-rows per thread in registers (64 VGPRs), pinned so the compiler
    // can't sink the loads into the j-loop.
    float4 a[RPT][DD / 4];
    #pragma unroll
    for (int r = 0; r < RPT; ++r) {
        const int i = h * 128 + r * 64 + lane;
        const float4* ar =
            (const float4*)(Arow_base + ((size_t)b * NN + i) * DD);
        #pragma unroll
        for (int k = 0; k < DD / 4; ++k) a[r][k] = ar[k];
    }
    #pragma unroll
    for (int r = 0; r < RPT; ++r)
        #pragma unroll
        for (int k = 0; k < DD / 4; ++k) pin4(a[r][k]);

    // |a|^2 with the 4-chain structure (identical to dot & b2 chains so the
    // xx/yy diagonal cancels to exact 0 before the clamp).
    float a2[RPT];
    #pragma unroll
    for (int r = 0; r < RPT; ++r) {
        float c0 = 0.f, c1 = 0.f, c2 = 0.f, c3 = 0.f;
        #pragma unroll
        for (int k = 0; k < DD / 4; ++k) {
            float4 v = a[r][k];
            c0 = fmaf(v.x, v.x, c0);
            c1 = fmaf(v.y, v.y, c1);
            c2 = fmaf(v.z, v.z, c2);
            c3 = fmaf(v.w, v.w, c3);
        }
        a2[r] = (c0 + c1) + (c2 + c3);
    }

    // Stage 32 B-rows (4 KB) in LDS: exactly 1 float4 store per thread.
    __shared__ float4 bs4[JCHUNK * (DD / 4)];
    __shared__ float b2s[JCHUNK];
    {
        const float4* bb =
            (const float4*)(Bcol_base + ((size_t)b * NN + s * JCHUNK) * DD);
        bs4[tid] = bb[tid];
    }
    __syncthreads();
    if (tid < JCHUNK) {
        float c0 = 0.f, c1 = 0.f, c2 = 0.f, c3 = 0.f;
        #pragma unroll
        for (int k = 0; k < DD / 4; ++k) {
            float4 v = bs4[tid * (DD / 4) + k];
            c0 = fmaf(v.x, v.x, c0);
            c1 = fmaf(v.y, v.y, c1);
            c2 = fmaf(v.z, v.z, c2);
            c3 = fmaf(v.w, v.w, c3);
        }
        b2s[tid] = (c0 + c1) + (c2 + c3);
    }
    __syncthreads();

    const float negw = -w[b] * (1.0f / (float)DD);

    float acc[RPT] = {0.f, 0.f};
    #pragma unroll 4
    for (int j = 0; j < SJ; ++j) {
        const int jg = jj * SJ + j;
        const float b2 = b2s[jg];
        float c[RPT][4];
        #pragma unroll
        for (int r = 0; r < RPT; ++r)
            c[r][0] = c[r][1] = c[r][2] = c[r][3] = 0.f;
        #pragma unroll
        for (int k = 0; k < DD / 4; ++k) {
            const float4 bv = bs4[jg * (DD / 4) + k];  // uniform -> broadcast
            #pragma unroll
            for (int r = 0; r < RPT; ++r) {
                c[r][0] = fmaf(a[r][k].x, bv.x, c[r][0]);
                c[r][1] = fmaf(a[r][k].y, bv.y, c[r][1]);
                c[r][2] = fmaf(a[r][k].z, bv.z, c[r][2]);
                c[r][3] = fmaf(a[r][k].w, bv.w, c[r][3]);
            }
        }
        #pragma unroll
        for (int r = 0; r < RPT; ++r) {
            const float dot = (c[r][0] + c[r][1]) + (c[r][2] + c[r][3]);
            float sq = fmaf(-2.0f, dot, a2[r] + b2);
            sq = fmaxf(sq, 1e-8f);   // folds norm clamp: sqrt(1e-8) = 1e-4
            acc[r] += __expf(negw * __builtin_amdgcn_sqrtf(sq));
        }
    }

    // Deterministic block reduction: wave shuffle + fixed-order cross-wave.
    float tsum = acc[0] + acc[1];
    #pragma unroll
    for (int off = 32; off > 0; off >>= 1) tsum += __shfl_down(tsum, off, 64);
    __shared__ float red[TPB / 64];
    if (lane == 0) red[wave] = tsum;
    __syncthreads();
    if (tid == 0) {
        const float bsum = (red[0] + red[1]) + (red[2] + red[3]);
        const float weight = (type == 2) ? -2.0f : 1.0f;
        const float scale  = weight / ((float)NN * (float)NN * (float)BB);
        partials[blk] = bsum * scale;
    }
}

// Final deterministic reduction of NPART partials in double.
__global__ __launch_bounds__(256) void mmd_reduce(
    const float* __restrict__ partials, float* __restrict__ out) {
    double acc = 0.0;
    #pragma unroll
    for (int t = 0; t < NPART / 256; ++t)
        acc += (double)partials[threadIdx.x + t * 256];
    #pragma unroll
    for (int off = 32; off > 0; off >>= 1) acc += __shfl_down(acc, off, 64);
    __shared__ double red[4];
    if ((threadIdx.x & 63) == 0) red[threadIdx.x >> 6] = acc;
    __syncthreads();
    if (threadIdx.x == 0)
        out[0] = (float)((red[0] + red[1]) + (red[2] + red[3]));
}

extern "C" void kernel_launch(void* const* d_in, const int* in_sizes, int n_in,
                              void* d_out, int out_size, void* d_ws, size_t ws_size,
                              hipStream_t stream) {
    const float* x = (const float*)d_in[0];
    const float* y = (const float*)d_in[1];
    const float* w = (const float*)d_in[2];
    float* out = (float*)d_out;
    float* partials = (float*)d_ws;  // NPART floats

    mmd_partial<<<NPART, TPB, 0, stream>>>(x, y, w, partials);
    mmd_reduce<<<1, 256, 0, stream>>>(partials, out);
}